// Round 11
// baseline (387.002 us; speedup 1.0000x reference)
//
#include <hip/hip_runtime.h>

// log-ODE Neural CDE. B=32 chains, 32 windows, Heun = 2 evals/window.
// fp32 in/out, f32 accum, f16 weights/activations (v_dot2_f32_f16).
// 1024 threads (16 waves, 4/SIMD — grid is 32 blocks = 1 block/CU, so block
// size IS the occupancy). 1024-thr blocks are hard-capped at 64 VGPRs
// (R7/R8/R9), so W3 lives in LDS ([colblock][row] layout: lane-pair 2-way
// aliasing = free per m136); W1 half-row (16 regs) + W2 quarter-row (8 regs)
// stay in registers. ~24 persistent + temps < 64 => no hot-loop spills.
#define NBATCH 32
#define LPATH  513
#define NWIN   32
#define LSIG   36
#define DSTR   136   // [dir] stride sD1/sD2 (f16) = 17 uint4
#define USTR   72    // [dir] stride sU (f16) = 9 uint4

typedef unsigned int u32;
typedef _Float16 h2 __attribute__((ext_vector_type(2)));

__device__ __forceinline__ u32 pkh(float a, float b){
  return __builtin_bit_cast(u32, __builtin_amdgcn_cvt_pkrtz(a, b));
}
__device__ __forceinline__ float dot2(u32 a, u32 b, float c){
#if __has_builtin(__builtin_amdgcn_fdot2)
  return __builtin_amdgcn_fdot2(__builtin_bit_cast(h2,a),
                                __builtin_bit_cast(h2,b), c, false);
#else
  h2 x = __builtin_bit_cast(h2,a), y = __builtin_bit_cast(h2,b);
  return c + (float)x[0]*(float)y[0] + (float)x[1]*(float)y[1];
#endif
}
__device__ __forceinline__ float tanh_fast(float x){
  float e = __expf(2.f*x);
  return 1.f - 2.f/(e+1.f);
}

extern "C" __global__ __launch_bounds__(1024)
void cde_kernel(const float* __restrict__ cv,
                const float* __restrict__ Wi1g, const float* __restrict__ bi1g,
                const float* __restrict__ Wi2g, const float* __restrict__ bi2g,
                const float* __restrict__ W1g,  const float* __restrict__ b1g,
                const float* __restrict__ W2g,  const float* __restrict__ b2g,
                const float* __restrict__ W3g,  const float* __restrict__ b3g,
                const float* __restrict__ Wrg,  const float* __restrict__ brg,
                const float* __restrict__ shg,
                float* __restrict__ outp)
{
  // ---- LDS (~151 KB of 160 KB) ----
  __shared__ __align__(16) uint4 sW3[16*512];  // 128 KB: [cb][row], cb=hh*8+q
  __shared__ float sG[NWIN*LSIG];
  __shared__ __align__(16) float sF[512];
  __shared__ float sCon[512];
  __shared__ float sB3[512];
  __shared__ float sB1[128], sB2[128];
  __shared__ __align__(16) float sWr[256];
  __shared__ float sBr[4], sSh[1];
  __shared__ float sC[64];
  __shared__ float sY[64], sK1[64], sLw[64];
  __shared__ __align__(16) _Float16 sYinp[64];
  __shared__ __align__(16) _Float16 sH1[128];
  __shared__ __align__(16) _Float16 sH2[128];
  __shared__ __align__(16) _Float16 sU [8*USTR];
  __shared__ __align__(16) _Float16 sD1[8*DSTR];
  __shared__ __align__(16) _Float16 sD2[8*DSTR];

  const int t   = threadIdx.x;       // 0..1023
  const int b   = blockIdx.x;
  const int r   = t >> 3;            // 0..127  (ph1/2/4/5 row)
  const int m   = t & 1;             // 32-col half (ph1/ph4, W1)
  const int qt  = t & 3;             // 16-col quarter (ph2/ph5, W2)
  const int dg4 = (t >> 1) & 3;      // ph4 dir-pair
  const int dg5 = (t >> 2) & 1;      // ph5 dir-quad
  const int r2  = t >> 1;            // 0..511  (ph3/6 row)
  const int hh  = t & 1;             // 64-col half (W3)
  const int j6  = r2 >> 6;           // dir for ph3/6 row block

  // ---- init biases / readout ----
  if (t < 512) sB3[t] = b3g[t];
  if (t < 128){ sB1[t] = b1g[t]; sB2[t] = b2g[t]; }
  if (t < 256) sWr[t] = Wrg[t];
  if (t < 4)   sBr[t] = brg[t];
  if (t == 0)  sSh[0] = shg[0];

  // ---- stage W3 into LDS as f16 pairs, [cb][row] layout ----
  {
    const float4* W3f4 = (const float4*)W3g;
    for (int tu = t; tu < 8192; tu += 1024){
      int rr = tu >> 4, cb = tu & 15;
      float4 a = W3f4[rr*32 + cb*2];
      float4 c = W3f4[rr*32 + cb*2 + 1];
      uint4 o;
      o.x = pkh(a.x, a.y); o.y = pkh(a.z, a.w);
      o.z = pkh(c.x, c.y); o.w = pkh(c.z, c.w);
      sW3[cb*512 + rr] = o;
    }
  }

  // ---- depth-2 Lyndon log-signatures, one window per thread (t<32) ----
  if (t < NWIN){
    const float4* cv4 = (const float4*)cv;
    const int base = (b*LPATH + t*16)*2;
    float cur[8], pre[8], acc[8], lv[28];
    { float4 a = cv4[base], d = cv4[base+1];
      cur[0]=a.x;cur[1]=a.y;cur[2]=a.z;cur[3]=a.w;
      cur[4]=d.x;cur[5]=d.y;cur[6]=d.z;cur[7]=d.w; }
    #pragma unroll
    for (int d=0; d<8; d++){ pre[d]=0.f; acc[d]=0.f; }
    #pragma unroll
    for (int p=0; p<28; p++) lv[p]=0.f;
    for (int w=1; w<=16; w++){
      float nxt[8], inc[8];
      { float4 a = cv4[base+2*w], d = cv4[base+2*w+1];
        nxt[0]=a.x;nxt[1]=a.y;nxt[2]=a.z;nxt[3]=a.w;
        nxt[4]=d.x;nxt[5]=d.y;nxt[6]=d.z;nxt[7]=d.w; }
      #pragma unroll
      for (int d=0; d<8; d++) inc[d] = nxt[d]-cur[d];
      int p=0;
      #pragma unroll
      for (int i=0; i<8; i++)
        #pragma unroll
        for (int j2=i+1; j2<8; j2++){ lv[p] += pre[i]*inc[j2] - pre[j2]*inc[i]; p++; }
      #pragma unroll
      for (int d=0; d<8; d++){ acc[d]+=inc[d]; pre[d]+=inc[d]; cur[d]=nxt[d]; }
    }
    float* gd = &sG[t*LSIG];
    #pragma unroll
    for (int d=0; d<8; d++) gd[d] = acc[d];
    #pragma unroll
    for (int p=0; p<28; p++) gd[8+p] = 0.5f*lv[p];
  }

  // ---- y0 = Wi2 @ lipswish(Wi1 @ x0 + bi1) + bi2 ----
  if (t < 64){
    float z = bi1g[t];
    #pragma unroll
    for (int d=0; d<8; d++) z += Wi1g[t*8+d] * cv[(b*LPATH)*8 + d];
    float s = 1.f/(1.f+__expf(-z));
    sLw[t] = 0.909f*z*s;
  }
  __syncthreads();
  if (t < 64){
    float z = bi2g[t];
    #pragma unroll 8
    for (int k=0; k<64; k++) z += Wi2g[t*64+k] * sLw[k];
    sY[t] = z;
    sYinp[t] = (_Float16)z;
  }
  __syncthreads();
  if (t < 4){
    float z = sBr[t] + sSh[0];
    #pragma unroll 8
    for (int a=0; a<64; a++) z += sWr[t*64+a]*sY[a];
    outp[(b*33 + 0)*4 + t] = z;
  }

  // ---- per-thread weight regs: W1 half-row 16 + W2 quarter-row 8 = 24 ----
  u32 w1h[16], w2q[8];
  {
    const float2* W1f2 = (const float2*)W1g;
    #pragma unroll
    for (int i=0; i<16; i++){ float2 v = W1f2[r*32 + m*16 + i]; w1h[i] = pkh(v.x, v.y); }
    const float2* W2f2 = (const float2*)W2g;
    #pragma unroll
    for (int i=0; i<8; i++){ float2 v = W2f2[r*64 + qt*8 + i]; w2q[i] = pkh(v.x, v.y); }
  }

  // One vector-field eval. mode 0: k1 (+fused sC, readout). mode 1: k2+Heun.
  auto EVAL = [&](const float* gcur, int mode, int s){
    __syncthreads();
    float dp1, dp2, fr;
    // ph1: z1 = W1@y + b1. (r,m): 32-col half, 16 dot2, 1 shfl.
    {
      if (mode == 0){
        if (t < 64){                          // bracket coeffs C[j*8+i]
          int j = t >> 3, i = t & 7;
          float v = 0.f;
          if (i < j)      v =  gcur[8 + (7*i - (i*(i-1))/2 + (j-i-1))];
          else if (i > j) v = -gcur[8 + (7*j - (j*(j-1))/2 + (i-j-1))];
          sC[t] = v;
        }
        if (s > 0 && t >= 1016 && t < 1020){  // readout of incoming y_s
          int o = t - 1016;
          float z = sBr[o] + sSh[0];
          const float4* wr4 = (const float4*)&sWr[o*64];
          const float4* y4f = (const float4*)sY;
          #pragma unroll
          for (int q=0; q<16; q++){
            float4 w = wr4[q], y = y4f[q];
            z += w.x*y.x + w.y*y.y + w.z*y.z + w.w*y.w;
          }
          outp[(b*33 + s)*4 + o] = z;
        }
      }
      const uint4* y4 = (const uint4*)sYinp;
      uint4 a = y4[m*4+0], bb = y4[m*4+1], cc = y4[m*4+2], dd = y4[m*4+3];
      float z0 = dot2(w1h[0], a.x, 0.f), z1 = dot2(w1h[1], a.y, 0.f);
      z0 = dot2(w1h[2],  a.z, z0);  z1 = dot2(w1h[3],  a.w, z1);
      z0 = dot2(w1h[4],  bb.x, z0); z1 = dot2(w1h[5],  bb.y, z1);
      z0 = dot2(w1h[6],  bb.z, z0); z1 = dot2(w1h[7],  bb.w, z1);
      z0 = dot2(w1h[8],  cc.x, z0); z1 = dot2(w1h[9],  cc.y, z1);
      z0 = dot2(w1h[10], cc.z, z0); z1 = dot2(w1h[11], cc.w, z1);
      z0 = dot2(w1h[12], dd.x, z0); z1 = dot2(w1h[13], dd.y, z1);
      z0 = dot2(w1h[14], dd.z, z0); z1 = dot2(w1h[15], dd.w, z1);
      float z = z0 + z1;
      z += __shfl_xor(z, 1);
      z += sB1[r];
      float sg = 1.f/(1.f+__expf(-z));
      dp1 = 0.909f*sg*(1.f + z*(1.f-sg));
      if ((t & 7) == 0) sH1[r] = (_Float16)(0.909f*z*sg);
    }
    __syncthreads();
    // ph2: z2 = W2@h1 + b2. (r,qt): 16-col quarter, 8 dot2, 2 shfl.
    {
      const uint4* h4 = (const uint4*)sH1;
      uint4 a = h4[qt*2], bb = h4[qt*2+1];
      float z0 = dot2(w2q[0], a.x, 0.f), z1 = dot2(w2q[1], a.y, 0.f);
      z0 = dot2(w2q[2], a.z, z0);  z1 = dot2(w2q[3], a.w, z1);
      z0 = dot2(w2q[4], bb.x, z0); z1 = dot2(w2q[5], bb.y, z1);
      z0 = dot2(w2q[6], bb.z, z0); z1 = dot2(w2q[7], bb.w, z1);
      float z = z0 + z1;
      z += __shfl_xor(z, 1); z += __shfl_xor(z, 2);
      z += sB2[r];
      float sg = 1.f/(1.f+__expf(-z));
      dp2 = 0.909f*sg*(1.f + z*(1.f-sg));
      if ((t & 7) == 0) sH2[r] = (_Float16)(0.909f*z*sg);
    }
    __syncthreads();
    // ph3: f = tanh(W3@h2 + b3). (r2,hh): 64-col half from LDS W3, 1 shfl.
    {
      const uint4* h4 = (const uint4*)sH2;
      float a0=0.f, a1=0.f;
      #pragma unroll 2
      for (int q=0; q<8; q++){
        uint4 w = sW3[(hh*8+q)*512 + r2];
        uint4 v = h4[hh*8 + q];
        a0 = dot2(w.x, v.x, a0); a1 = dot2(w.y, v.y, a1);
        a0 = dot2(w.z, v.z, a0); a1 = dot2(w.w, v.w, a1);
      }
      float z = a0 + a1;
      z += __shfl_xor(z, 1);
      fr = tanh_fast(z + sB3[r2]);
      if (hh == 0) sF[r2] = fr;
    }
    __syncthreads();
    // U-fold: u_j[bb] = sum_i C[j,i] f[i*64+bb]; threads t,t+512 duplicate.
    {
      int jj = (t >> 6) & 7, bb = t & 63;
      float u = 0.f;
      #pragma unroll
      for (int i=0; i<8; i++) u += sC[jj*8 + i] * sF[i*64 + bb];
      sU[jj*USTR + bb] = (_Float16)u;
    }
    __syncthreads();
    // ph4: D1[d] = dp1*(W1@u_d). (r,m,dg4): dirs 2dg4,2dg4+1 x 32-col half.
    {
      const uint4* u4 = (const uint4*)sU;
      float a0=0.f, a1=0.f;
      #pragma unroll
      for (int q=0; q<4; q++){
        uint4 va = u4[(2*dg4)*9 + m*4 + q];
        a0 = dot2(w1h[4*q+0], va.x, a0); a0 = dot2(w1h[4*q+1], va.y, a0);
        a0 = dot2(w1h[4*q+2], va.z, a0); a0 = dot2(w1h[4*q+3], va.w, a0);
        uint4 vb = u4[(2*dg4+1)*9 + m*4 + q];
        a1 = dot2(w1h[4*q+0], vb.x, a1); a1 = dot2(w1h[4*q+1], vb.y, a1);
        a1 = dot2(w1h[4*q+2], vb.z, a1); a1 = dot2(w1h[4*q+3], vb.w, a1);
      }
      a0 += __shfl_xor(a0, 1);
      a1 += __shfl_xor(a1, 1);
      if (m == 0){
        sD1[(2*dg4)*DSTR   + r] = (_Float16)(dp1*a0);
        sD1[(2*dg4+1)*DSTR + r] = (_Float16)(dp1*a1);
      }
    }
    __syncthreads();
    // ph5: D2[d] = dp2*(W2@D1[d]). (r,qt,dg5): dirs 4dg5..+3 x 16-col qtr.
    {
      const uint4* d4 = (const uint4*)sD1;
      float ac[4] = {0.f,0.f,0.f,0.f};
      #pragma unroll
      for (int k=0; k<4; k++){
        int dir = 4*dg5 + k;
        uint4 a = d4[dir*17 + qt*2], bb = d4[dir*17 + qt*2 + 1];
        float z0 = dot2(w2q[0], a.x, 0.f), z1 = dot2(w2q[1], a.y, 0.f);
        z0 = dot2(w2q[2], a.z, z0);  z1 = dot2(w2q[3], a.w, z1);
        z0 = dot2(w2q[4], bb.x, z0); z1 = dot2(w2q[5], bb.y, z1);
        z0 = dot2(w2q[6], bb.z, z0); z1 = dot2(w2q[7], bb.w, z1);
        ac[k] = z0 + z1;
      }
      #pragma unroll
      for (int k=0; k<4; k++){
        ac[k] += __shfl_xor(ac[k], 1);
        ac[k] += __shfl_xor(ac[k], 2);
      }
      if (qt == 0){
        #pragma unroll
        for (int k=0; k<4; k++)
          sD2[(4*dg5+k)*DSTR + r] = (_Float16)(dp2*ac[k]);
      }
    }
    __syncthreads();
    // ph6: T3[r2] = W3[r2]·D2[j6]; contribution. (r2,hh), 1 shfl.
    {
      const uint4* d4 = (const uint4*)&sD2[j6*DSTR];
      float a0=0.f, a1=0.f;
      #pragma unroll 2
      for (int q=0; q<8; q++){
        uint4 w = sW3[(hh*8+q)*512 + r2];
        uint4 v = d4[hh*8 + q];
        a0 = dot2(w.x, v.x, a0); a1 = dot2(w.y, v.y, a1);
        a0 = dot2(w.z, v.z, a0); a1 = dot2(w.w, v.w, a1);
      }
      float z = a0 + a1;
      z += __shfl_xor(z, 1);
      if (hh == 0) sCon[r2] = gcur[j6]*fr + (1.f - fr*fr)*z;
    }
    __syncthreads();
    // ph7: k[a] = sum_j contrib; fused Heun updates.
    if (t < 64){
      float k = 0.f;
      #pragma unroll
      for (int j=0; j<8; j++) k += sCon[j*64 + t];
      if (mode == 0){
        sK1[t] = k;
        sYinp[t] = (_Float16)(sY[t] + k);
      } else {
        float yn = sY[t] + 0.5f*(sK1[t] + k);
        sY[t] = yn;
        sYinp[t] = (_Float16)yn;
      }
    }
  };

  // ---- main scan over windows ----
  for (int s = 0; s < NWIN; s++){
    const float* gcur = &sG[s*LSIG];
    EVAL(gcur, 0, s);
    EVAL(gcur, 1, s);
  }
  __syncthreads();
  if (t < 4){
    float z = sBr[t] + sSh[0];
    #pragma unroll 8
    for (int a=0; a<64; a++) z += sWr[t*64+a]*sY[a];
    outp[(b*33 + 32)*4 + t] = z;
  }
}

extern "C" void kernel_launch(void* const* d_in, const int* in_sizes, int n_in,
                              void* d_out, int out_size, void* d_ws, size_t ws_size,
                              hipStream_t stream) {
  cde_kernel<<<dim3(NBATCH), dim3(1024), 0, stream>>>(
      (const float*)d_in[0],
      (const float*)d_in[1],  (const float*)d_in[2],
      (const float*)d_in[3],  (const float*)d_in[4],
      (const float*)d_in[5],  (const float*)d_in[6],
      (const float*)d_in[7],  (const float*)d_in[8],
      (const float*)d_in[9],  (const float*)d_in[10],
      (const float*)d_in[11], (const float*)d_in[12],
      (const float*)d_in[13],
      (float*)d_out);
}

// Round 12
// 361.722 us; speedup vs baseline: 1.0699x; 1.0699x over previous
//
#include <hip/hip_runtime.h>

// log-ODE Neural CDE. B=32 chains, 32 windows, Heun = 2 evals/window.
// fp32 in/out, f32 accum, f16 weights/activations (v_dot2_f32_f16).
// 1024 threads (16 waves, 4/SIMD; grid = 32 blocks = 1 block/CU). 1024-thr
// blocks are VGPR-capped at 64 (R7/R8/R9), so W3 lives in LDS. R12 layout:
// sW3[(q*512+row)*2 + hh] -> lane t reads consecutive 16B (t>>1 = row pairs,
// t&1 = col half) => conflict-free coalesced ds_read_b128 (R11's [cb][row]
// layout was ~8-way conflicted: 4.47M conflict cycles, 19% of runtime).
#define NBATCH 32
#define LPATH  513
#define NWIN   32
#define LSIG   36
#define DSTR   136   // [dir] stride sD1/sD2 (f16) = 17 uint4
#define USTR   72    // [dir] stride sU (f16) = 9 uint4

typedef unsigned int u32;
typedef _Float16 h2 __attribute__((ext_vector_type(2)));

__device__ __forceinline__ u32 pkh(float a, float b){
  return __builtin_bit_cast(u32, __builtin_amdgcn_cvt_pkrtz(a, b));
}
__device__ __forceinline__ float dot2(u32 a, u32 b, float c){
#if __has_builtin(__builtin_amdgcn_fdot2)
  return __builtin_amdgcn_fdot2(__builtin_bit_cast(h2,a),
                                __builtin_bit_cast(h2,b), c, false);
#else
  h2 x = __builtin_bit_cast(h2,a), y = __builtin_bit_cast(h2,b);
  return c + (float)x[0]*(float)y[0] + (float)x[1]*(float)y[1];
#endif
}
__device__ __forceinline__ float tanh_fast(float x){
  float e = __expf(2.f*x);
  return 1.f - 2.f/(e+1.f);
}

extern "C" __global__ __launch_bounds__(1024)
void cde_kernel(const float* __restrict__ cv,
                const float* __restrict__ Wi1g, const float* __restrict__ bi1g,
                const float* __restrict__ Wi2g, const float* __restrict__ bi2g,
                const float* __restrict__ W1g,  const float* __restrict__ b1g,
                const float* __restrict__ W2g,  const float* __restrict__ b2g,
                const float* __restrict__ W3g,  const float* __restrict__ b3g,
                const float* __restrict__ Wrg,  const float* __restrict__ brg,
                const float* __restrict__ shg,
                float* __restrict__ outp)
{
  // ---- LDS (~151 KB of 160 KB) ----
  __shared__ __align__(16) uint4 sW3[8192];    // 128 KB: [(q*512+row)*2+hh]
  __shared__ float sG[NWIN*LSIG];
  __shared__ __align__(16) float sF[512];
  __shared__ float sCon[512];
  __shared__ float sB3[512];
  __shared__ float sB1[128], sB2[128];
  __shared__ __align__(16) float sWr[256];
  __shared__ float sBr[4], sSh[1];
  __shared__ float sC[64];
  __shared__ float sY[64], sK1[64], sLw[64];
  __shared__ __align__(16) _Float16 sYinp[64];
  __shared__ __align__(16) _Float16 sH1[128];
  __shared__ __align__(16) _Float16 sH2[128];
  __shared__ __align__(16) _Float16 sU [8*USTR];
  __shared__ __align__(16) _Float16 sD1[8*DSTR];
  __shared__ __align__(16) _Float16 sD2[8*DSTR];

  const int t   = threadIdx.x;       // 0..1023
  const int b   = blockIdx.x;
  const int r   = t >> 3;            // 0..127  (ph1/2/4/5 row)
  const int m   = t & 1;             // 32-col half (ph1/ph4, W1)
  const int qt  = t & 3;             // 16-col quarter (ph2/ph5, W2)
  const int dg4 = (t >> 1) & 3;      // ph4 dir-pair
  const int dg5 = (t >> 2) & 1;      // ph5 dir-quad
  const int r2  = t >> 1;            // 0..511  (ph3/6 row)
  const int hh  = t & 1;             // 64-col half (W3)
  const int j6  = r2 >> 6;           // dir for ph3/6 row block

  // ---- init biases / readout ----
  if (t < 512) sB3[t] = b3g[t];
  if (t < 128){ sB1[t] = b1g[t]; sB2[t] = b2g[t]; }
  if (t < 256) sWr[t] = Wrg[t];
  if (t < 4)   sBr[t] = brg[t];
  if (t == 0)  sSh[0] = shg[0];

  // ---- stage W3 into LDS as f16 pairs, interleaved-coalesced layout ----
  {
    const float4* W3f4 = (const float4*)W3g;
    for (int tu = t; tu < 8192; tu += 1024){
      int rr = tu >> 4, cb2 = tu & 15;       // cb2 = col block of 8
      float4 a = W3f4[rr*32 + cb2*2];
      float4 c = W3f4[rr*32 + cb2*2 + 1];
      uint4 o;
      o.x = pkh(a.x, a.y); o.y = pkh(a.z, a.w);
      o.z = pkh(c.x, c.y); o.w = pkh(c.z, c.w);
      sW3[((cb2 & 7)*512 + rr)*2 + (cb2 >> 3)] = o;
    }
  }

  // ---- depth-2 Lyndon log-signatures, one window per thread (t<32) ----
  if (t < NWIN){
    const float4* cv4 = (const float4*)cv;
    const int base = (b*LPATH + t*16)*2;
    float cur[8], pre[8], acc[8], lv[28];
    { float4 a = cv4[base], d = cv4[base+1];
      cur[0]=a.x;cur[1]=a.y;cur[2]=a.z;cur[3]=a.w;
      cur[4]=d.x;cur[5]=d.y;cur[6]=d.z;cur[7]=d.w; }
    #pragma unroll
    for (int d=0; d<8; d++){ pre[d]=0.f; acc[d]=0.f; }
    #pragma unroll
    for (int p=0; p<28; p++) lv[p]=0.f;
    for (int w=1; w<=16; w++){
      float nxt[8], inc[8];
      { float4 a = cv4[base+2*w], d = cv4[base+2*w+1];
        nxt[0]=a.x;nxt[1]=a.y;nxt[2]=a.z;nxt[3]=a.w;
        nxt[4]=d.x;nxt[5]=d.y;nxt[6]=d.z;nxt[7]=d.w; }
      #pragma unroll
      for (int d=0; d<8; d++) inc[d] = nxt[d]-cur[d];
      int p=0;
      #pragma unroll
      for (int i=0; i<8; i++)
        #pragma unroll
        for (int j2=i+1; j2<8; j2++){ lv[p] += pre[i]*inc[j2] - pre[j2]*inc[i]; p++; }
      #pragma unroll
      for (int d=0; d<8; d++){ acc[d]+=inc[d]; pre[d]+=inc[d]; cur[d]=nxt[d]; }
    }
    float* gd = &sG[t*LSIG];
    #pragma unroll
    for (int d=0; d<8; d++) gd[d] = acc[d];
    #pragma unroll
    for (int p=0; p<28; p++) gd[8+p] = 0.5f*lv[p];
  }

  // ---- y0 = Wi2 @ lipswish(Wi1 @ x0 + bi1) + bi2 ----
  if (t < 64){
    float z = bi1g[t];
    #pragma unroll
    for (int d=0; d<8; d++) z += Wi1g[t*8+d] * cv[(b*LPATH)*8 + d];
    float s = 1.f/(1.f+__expf(-z));
    sLw[t] = 0.909f*z*s;
  }
  __syncthreads();
  if (t < 64){
    float z = bi2g[t];
    #pragma unroll 8
    for (int k=0; k<64; k++) z += Wi2g[t*64+k] * sLw[k];
    sY[t] = z;
    sYinp[t] = (_Float16)z;
  }
  __syncthreads();
  if (t < 4){
    float z = sBr[t] + sSh[0];
    #pragma unroll 8
    for (int a=0; a<64; a++) z += sWr[t*64+a]*sY[a];
    outp[(b*33 + 0)*4 + t] = z;
  }

  // ---- per-thread weight regs: W1 half-row 16 + W2 quarter-row 8 = 24 ----
  u32 w1h[16], w2q[8];
  {
    const float2* W1f2 = (const float2*)W1g;
    #pragma unroll
    for (int i=0; i<16; i++){ float2 v = W1f2[r*32 + m*16 + i]; w1h[i] = pkh(v.x, v.y); }
    const float2* W2f2 = (const float2*)W2g;
    #pragma unroll
    for (int i=0; i<8; i++){ float2 v = W2f2[r*64 + qt*8 + i]; w2q[i] = pkh(v.x, v.y); }
  }

  // One vector-field eval. mode 0: k1 (+fused sC, readout). mode 1: k2+Heun.
  auto EVAL = [&](const float* gcur, int mode, int s){
    __syncthreads();
    float dp1, dp2, fr;
    // ph1: z1 = W1@y + b1. (r,m): 32-col half, 16 dot2, 1 shfl.
    {
      if (mode == 0){
        if (t < 64){                          // bracket coeffs C[j*8+i]
          int j = t >> 3, i = t & 7;
          float v = 0.f;
          if (i < j)      v =  gcur[8 + (7*i - (i*(i-1))/2 + (j-i-1))];
          else if (i > j) v = -gcur[8 + (7*j - (j*(j-1))/2 + (i-j-1))];
          sC[t] = v;
        }
        if (s > 0 && t >= 1016 && t < 1020){  // readout of incoming y_s
          int o = t - 1016;
          float z = sBr[o] + sSh[0];
          const float4* wr4 = (const float4*)&sWr[o*64];
          const float4* y4f = (const float4*)sY;
          #pragma unroll
          for (int q=0; q<16; q++){
            float4 w = wr4[q], y = y4f[q];
            z += w.x*y.x + w.y*y.y + w.z*y.z + w.w*y.w;
          }
          outp[(b*33 + s)*4 + o] = z;
        }
      }
      const uint4* y4 = (const uint4*)sYinp;
      uint4 a = y4[m*4+0], bb = y4[m*4+1], cc = y4[m*4+2], dd = y4[m*4+3];
      float z0 = dot2(w1h[0], a.x, 0.f), z1 = dot2(w1h[1], a.y, 0.f);
      z0 = dot2(w1h[2],  a.z, z0);  z1 = dot2(w1h[3],  a.w, z1);
      z0 = dot2(w1h[4],  bb.x, z0); z1 = dot2(w1h[5],  bb.y, z1);
      z0 = dot2(w1h[6],  bb.z, z0); z1 = dot2(w1h[7],  bb.w, z1);
      z0 = dot2(w1h[8],  cc.x, z0); z1 = dot2(w1h[9],  cc.y, z1);
      z0 = dot2(w1h[10], cc.z, z0); z1 = dot2(w1h[11], cc.w, z1);
      z0 = dot2(w1h[12], dd.x, z0); z1 = dot2(w1h[13], dd.y, z1);
      z0 = dot2(w1h[14], dd.z, z0); z1 = dot2(w1h[15], dd.w, z1);
      float z = z0 + z1;
      z += __shfl_xor(z, 1);
      z += sB1[r];
      float sg = 1.f/(1.f+__expf(-z));
      dp1 = 0.909f*sg*(1.f + z*(1.f-sg));
      if ((t & 7) == 0) sH1[r] = (_Float16)(0.909f*z*sg);
    }
    __syncthreads();
    // ph2: z2 = W2@h1 + b2. (r,qt): 16-col quarter, 8 dot2, 2 shfl.
    {
      const uint4* h4 = (const uint4*)sH1;
      uint4 a = h4[qt*2], bb = h4[qt*2+1];
      float z0 = dot2(w2q[0], a.x, 0.f), z1 = dot2(w2q[1], a.y, 0.f);
      z0 = dot2(w2q[2], a.z, z0);  z1 = dot2(w2q[3], a.w, z1);
      z0 = dot2(w2q[4], bb.x, z0); z1 = dot2(w2q[5], bb.y, z1);
      z0 = dot2(w2q[6], bb.z, z0); z1 = dot2(w2q[7], bb.w, z1);
      float z = z0 + z1;
      z += __shfl_xor(z, 1); z += __shfl_xor(z, 2);
      z += sB2[r];
      float sg = 1.f/(1.f+__expf(-z));
      dp2 = 0.909f*sg*(1.f + z*(1.f-sg));
      if ((t & 7) == 0) sH2[r] = (_Float16)(0.909f*z*sg);
    }
    __syncthreads();
    // ph3: f = tanh(W3@h2 + b3). (r2,hh): coalesced W3 reads, 1 shfl.
    {
      const uint4* h4 = (const uint4*)sH2;
      float a0=0.f, a1=0.f;
      #pragma unroll 2
      for (int q=0; q<8; q++){
        uint4 w = sW3[(q*512 + r2)*2 + hh];
        uint4 v = h4[hh*8 + q];
        a0 = dot2(w.x, v.x, a0); a1 = dot2(w.y, v.y, a1);
        a0 = dot2(w.z, v.z, a0); a1 = dot2(w.w, v.w, a1);
      }
      float z = a0 + a1;
      z += __shfl_xor(z, 1);
      fr = tanh_fast(z + sB3[r2]);
      if (hh == 0) sF[r2] = fr;
    }
    __syncthreads();
    // U-fold: u_j[bb] = sum_i C[j,i] f[i*64+bb]; threads t,t+512 duplicate.
    {
      int jj = (t >> 6) & 7, bb = t & 63;
      float u = 0.f;
      #pragma unroll
      for (int i=0; i<8; i++) u += sC[jj*8 + i] * sF[i*64 + bb];
      sU[jj*USTR + bb] = (_Float16)u;
    }
    __syncthreads();
    // ph4: D1[d] = dp1*(W1@u_d). (r,m,dg4): dirs 2dg4,2dg4+1 x 32-col half.
    {
      const uint4* u4 = (const uint4*)sU;
      float a0=0.f, a1=0.f;
      #pragma unroll
      for (int q=0; q<4; q++){
        uint4 va = u4[(2*dg4)*9 + m*4 + q];
        a0 = dot2(w1h[4*q+0], va.x, a0); a0 = dot2(w1h[4*q+1], va.y, a0);
        a0 = dot2(w1h[4*q+2], va.z, a0); a0 = dot2(w1h[4*q+3], va.w, a0);
        uint4 vb = u4[(2*dg4+1)*9 + m*4 + q];
        a1 = dot2(w1h[4*q+0], vb.x, a1); a1 = dot2(w1h[4*q+1], vb.y, a1);
        a1 = dot2(w1h[4*q+2], vb.z, a1); a1 = dot2(w1h[4*q+3], vb.w, a1);
      }
      a0 += __shfl_xor(a0, 1);
      a1 += __shfl_xor(a1, 1);
      if (m == 0){
        sD1[(2*dg4)*DSTR   + r] = (_Float16)(dp1*a0);
        sD1[(2*dg4+1)*DSTR + r] = (_Float16)(dp1*a1);
      }
    }
    __syncthreads();
    // ph5: D2[d] = dp2*(W2@D1[d]). (r,qt,dg5): dirs 4dg5..+3 x 16-col qtr.
    {
      const uint4* d4 = (const uint4*)sD1;
      float ac[4] = {0.f,0.f,0.f,0.f};
      #pragma unroll
      for (int k=0; k<4; k++){
        int dir = 4*dg5 + k;
        uint4 a = d4[dir*17 + qt*2], bb = d4[dir*17 + qt*2 + 1];
        float z0 = dot2(w2q[0], a.x, 0.f), z1 = dot2(w2q[1], a.y, 0.f);
        z0 = dot2(w2q[2], a.z, z0);  z1 = dot2(w2q[3], a.w, z1);
        z0 = dot2(w2q[4], bb.x, z0); z1 = dot2(w2q[5], bb.y, z1);
        z0 = dot2(w2q[6], bb.z, z0); z1 = dot2(w2q[7], bb.w, z1);
        ac[k] = z0 + z1;
      }
      #pragma unroll
      for (int k=0; k<4; k++){
        ac[k] += __shfl_xor(ac[k], 1);
        ac[k] += __shfl_xor(ac[k], 2);
      }
      if (qt == 0){
        #pragma unroll
        for (int k=0; k<4; k++)
          sD2[(4*dg5+k)*DSTR + r] = (_Float16)(dp2*ac[k]);
      }
    }
    __syncthreads();
    // ph6: T3[r2] = W3[r2]·D2[j6]; contribution. (r2,hh), 1 shfl.
    {
      const uint4* d4 = (const uint4*)&sD2[j6*DSTR];
      float a0=0.f, a1=0.f;
      #pragma unroll 2
      for (int q=0; q<8; q++){
        uint4 w = sW3[(q*512 + r2)*2 + hh];
        uint4 v = d4[hh*8 + q];
        a0 = dot2(w.x, v.x, a0); a1 = dot2(w.y, v.y, a1);
        a0 = dot2(w.z, v.z, a0); a1 = dot2(w.w, v.w, a1);
      }
      float z = a0 + a1;
      z += __shfl_xor(z, 1);
      if (hh == 0) sCon[r2] = gcur[j6]*fr + (1.f - fr*fr)*z;
    }
    __syncthreads();
    // ph7: k[a] = sum_j contrib; fused Heun updates.
    if (t < 64){
      float k = 0.f;
      #pragma unroll
      for (int j=0; j<8; j++) k += sCon[j*64 + t];
      if (mode == 0){
        sK1[t] = k;
        sYinp[t] = (_Float16)(sY[t] + k);
      } else {
        float yn = sY[t] + 0.5f*(sK1[t] + k);
        sY[t] = yn;
        sYinp[t] = (_Float16)yn;
      }
    }
  };

  // ---- main scan over windows ----
  for (int s = 0; s < NWIN; s++){
    const float* gcur = &sG[s*LSIG];
    EVAL(gcur, 0, s);
    EVAL(gcur, 1, s);
  }
  __syncthreads();
  if (t < 4){
    float z = sBr[t] + sSh[0];
    #pragma unroll 8
    for (int a=0; a<64; a++) z += sWr[t*64+a]*sY[a];
    outp[(b*33 + 32)*4 + t] = z;
  }
}

extern "C" void kernel_launch(void* const* d_in, const int* in_sizes, int n_in,
                              void* d_out, int out_size, void* d_ws, size_t ws_size,
                              hipStream_t stream) {
  cde_kernel<<<dim3(NBATCH), dim3(1024), 0, stream>>>(
      (const float*)d_in[0],
      (const float*)d_in[1],  (const float*)d_in[2],
      (const float*)d_in[3],  (const float*)d_in[4],
      (const float*)d_in[5],  (const float*)d_in[6],
      (const float*)d_in[7],  (const float*)d_in[8],
      (const float*)d_in[9],  (const float*)d_in[10],
      (const float*)d_in[11], (const float*)d_in[12],
      (const float*)d_in[13],
      (float*)d_out);
}

// Round 13
// 360.509 us; speedup vs baseline: 1.0735x; 1.0034x over previous
//
#include <hip/hip_runtime.h>

// log-ODE Neural CDE. B=32 chains, 32 windows, Heun = 2 evals/window.
// fp32 in/out, f32 accum, f16 weights/activations (v_dot2_f32_f16).
// 512 threads (8 waves, 2/SIMD), one block per batch element, W1/W2 halves +
// FULL W3 row per thread in registers (112 u32; (512,1) allows ~128+ VGPRs).
// R13: 6 barrier-phases per eval (was 8): U-fold folded into ph4 via in-reg
// C-combine (JVP linearity); ph7 folded into ph6 via row-permuted W3
// ownership (row = (t&7)*64 + t>>3) so k[a] is a 3-shfl lane reduction.
#define NBATCH 32
#define LPATH  513
#define NWIN   32
#define LSIG   36
#define DSTR   136   // [dir] stride sD1/sD2 (f16) = 17 uint4

typedef unsigned int u32;
typedef _Float16 h2 __attribute__((ext_vector_type(2)));

__device__ __forceinline__ u32 pkh(float a, float b){
  return __builtin_bit_cast(u32, __builtin_amdgcn_cvt_pkrtz(a, b));
}
__device__ __forceinline__ float dot2(u32 a, u32 b, float c){
#if __has_builtin(__builtin_amdgcn_fdot2)
  return __builtin_amdgcn_fdot2(__builtin_bit_cast(h2,a),
                                __builtin_bit_cast(h2,b), c, false);
#else
  h2 x = __builtin_bit_cast(h2,a), y = __builtin_bit_cast(h2,b);
  return c + (float)x[0]*(float)y[0] + (float)x[1]*(float)y[1];
#endif
}
__device__ __forceinline__ float tanh_fast(float x){
  float e = __expf(2.f*x);
  return 1.f - 2.f/(e+1.f);
}

extern "C" __global__ __launch_bounds__(512, 1)
void cde_kernel(const float* __restrict__ cv,
                const float* __restrict__ Wi1g, const float* __restrict__ bi1g,
                const float* __restrict__ Wi2g, const float* __restrict__ bi2g,
                const float* __restrict__ W1g,  const float* __restrict__ b1g,
                const float* __restrict__ W2g,  const float* __restrict__ b2g,
                const float* __restrict__ W3g,  const float* __restrict__ b3g,
                const float* __restrict__ Wrg,  const float* __restrict__ brg,
                const float* __restrict__ shg,
                float* __restrict__ outp)
{
  // ---- LDS (~16 KB) ----
  __shared__ float sG[NWIN*LSIG];
  __shared__ float sB3[512];
  __shared__ float sB1[128], sB2[128];
  __shared__ __align__(16) float sWr[256];
  __shared__ float sBr[4], sSh[1];
  __shared__ float sC[64];
  __shared__ float sY[64], sLw[64];
  __shared__ __align__(16) _Float16 sYinp[64];
  __shared__ __align__(16) _Float16 sH1[128];
  __shared__ __align__(16) _Float16 sH2[128];
  __shared__ __align__(16) _Float16 sFh[512];     // f16 tanh values
  __shared__ __align__(16) _Float16 sD1[8*DSTR];  // [dir][row]
  __shared__ __align__(16) _Float16 sD2[8*DSTR];  // [dir][row]

  const int t    = threadIdx.x;       // 0..511
  const int b    = blockIdx.x;
  const int r    = t >> 2;            // 0..127 (ph1/2/4/5 row)
  const int m    = t & 1;             // col half
  const int g    = (t >> 1) & 1;      // dir group (4 raw dirs / 4 D-dirs)
  const int jown = t & 7;             // owned dir  (ph3/6)
  const int aown = t >> 3;            // owned hid  (ph3/6)
  const int rowp = jown*64 + aown;    // owned W3 row (permuted)

  // ---- init biases / readout ----
  if (t < 512) sB3[t] = b3g[t];
  if (t < 128){ sB1[t] = b1g[t]; sB2[t] = b2g[t]; }
  if (t < 256) sWr[t] = Wrg[t];
  if (t < 4)   sBr[t] = brg[t];
  if (t == 0)  sSh[0] = shg[0];

  // ---- depth-2 Lyndon log-signatures, one window per thread (t<32) ----
  if (t < NWIN){
    const float4* cv4 = (const float4*)cv;
    const int base = (b*LPATH + t*16)*2;
    float cur[8], pre[8], acc[8], lv[28];
    { float4 a = cv4[base], d = cv4[base+1];
      cur[0]=a.x;cur[1]=a.y;cur[2]=a.z;cur[3]=a.w;
      cur[4]=d.x;cur[5]=d.y;cur[6]=d.z;cur[7]=d.w; }
    #pragma unroll
    for (int d=0; d<8; d++){ pre[d]=0.f; acc[d]=0.f; }
    #pragma unroll
    for (int p=0; p<28; p++) lv[p]=0.f;
    for (int w=1; w<=16; w++){
      float nxt[8], inc[8];
      { float4 a = cv4[base+2*w], d = cv4[base+2*w+1];
        nxt[0]=a.x;nxt[1]=a.y;nxt[2]=a.z;nxt[3]=a.w;
        nxt[4]=d.x;nxt[5]=d.y;nxt[6]=d.z;nxt[7]=d.w; }
      #pragma unroll
      for (int d=0; d<8; d++) inc[d] = nxt[d]-cur[d];
      int p=0;
      #pragma unroll
      for (int i=0; i<8; i++)
        #pragma unroll
        for (int j2=i+1; j2<8; j2++){ lv[p] += pre[i]*inc[j2] - pre[j2]*inc[i]; p++; }
      #pragma unroll
      for (int d=0; d<8; d++){ acc[d]+=inc[d]; pre[d]+=inc[d]; cur[d]=nxt[d]; }
    }
    float* gd = &sG[t*LSIG];
    #pragma unroll
    for (int d=0; d<8; d++) gd[d] = acc[d];
    #pragma unroll
    for (int p=0; p<28; p++) gd[8+p] = 0.5f*lv[p];
  }

  // ---- y0 = Wi2 @ lipswish(Wi1 @ x0 + bi1) + bi2 ----
  if (t < 64){
    float z = bi1g[t];
    #pragma unroll
    for (int d=0; d<8; d++) z += Wi1g[t*8+d] * cv[(b*LPATH)*8 + d];
    float s = 1.f/(1.f+__expf(-z));
    sLw[t] = 0.909f*z*s;
  }
  __syncthreads();
  if (t < 64){
    float z = bi2g[t];
    #pragma unroll 8
    for (int k=0; k<64; k++) z += Wi2g[t*64+k] * sLw[k];
    sY[t] = z;
    sYinp[t] = (_Float16)z;
  }
  __syncthreads();
  if (t < 4){
    float z = sBr[t] + sSh[0];
    #pragma unroll 8
    for (int a=0; a<64; a++) z += sWr[t*64+a]*sY[a];
    outp[(b*33 + 0)*4 + t] = z;
  }

  // ---- per-thread weight regs: W1 half 16 + W2 half 32 + W3 row 64 ----
  u32 w1h[16], w2h[32], w3r[64];
  {
    const float2* W1f2 = (const float2*)W1g;
    #pragma unroll
    for (int i=0; i<16; i++){ float2 v = W1f2[r*32 + m*16 + i]; w1h[i] = pkh(v.x, v.y); }
    const float2* W2f2 = (const float2*)W2g;
    #pragma unroll
    for (int i=0; i<32; i++){ float2 v = W2f2[r*64 + m*32 + i]; w2h[i] = pkh(v.x, v.y); }
    const float4* W3f4 = (const float4*)W3g;
    #pragma unroll
    for (int k=0; k<32; k++){
      float4 v = W3f4[rowp*32 + k];
      w3r[2*k]   = pkh(v.x, v.y);
      w3r[2*k+1] = pkh(v.z, v.w);
    }
  }

  float k1save = 0.f;    // k1 for Heun, lives in j0-lane registers

  // One vector-field eval. mode 0: k1 (+fused sC, readout). mode 1: k2+Heun.
  auto EVAL = [&](const float* gcur, int mode, int s){
    __syncthreads();                          // sYinp, sY, sC coherent
    float dp1, dp2, fr;
    // ph1: z1 = W1@y + b1. (r,m): 32-col half, 16 dot2, 1 shfl.
    {
      if (mode == 0){
        if (t < 64){                          // bracket coeffs C[j*8+i]
          int j = t >> 3, i = t & 7;
          float v = 0.f;
          if (i < j)      v =  gcur[8 + (7*i - (i*(i-1))/2 + (j-i-1))];
          else if (i > j) v = -gcur[8 + (7*j - (j*(j-1))/2 + (i-j-1))];
          sC[t] = v;
        }
        if (s > 0 && t >= 504 && t < 508){    // readout of incoming y_s
          int o = t - 504;
          float z = sBr[o] + sSh[0];
          const float4* wr4 = (const float4*)&sWr[o*64];
          const float4* y4f = (const float4*)sY;
          #pragma unroll
          for (int q=0; q<16; q++){
            float4 w = wr4[q], y = y4f[q];
            z += w.x*y.x + w.y*y.y + w.z*y.z + w.w*y.w;
          }
          outp[(b*33 + s)*4 + o] = z;
        }
      }
      const uint4* y4 = (const uint4*)sYinp;
      uint4 a = y4[m*4+0], bb = y4[m*4+1], cc = y4[m*4+2], dd = y4[m*4+3];
      float z0 = dot2(w1h[0], a.x, 0.f), z1 = dot2(w1h[1], a.y, 0.f);
      z0 = dot2(w1h[2],  a.z, z0);  z1 = dot2(w1h[3],  a.w, z1);
      z0 = dot2(w1h[4],  bb.x, z0); z1 = dot2(w1h[5],  bb.y, z1);
      z0 = dot2(w1h[6],  bb.z, z0); z1 = dot2(w1h[7],  bb.w, z1);
      z0 = dot2(w1h[8],  cc.x, z0); z1 = dot2(w1h[9],  cc.y, z1);
      z0 = dot2(w1h[10], cc.z, z0); z1 = dot2(w1h[11], cc.w, z1);
      z0 = dot2(w1h[12], dd.x, z0); z1 = dot2(w1h[13], dd.y, z1);
      z0 = dot2(w1h[14], dd.z, z0); z1 = dot2(w1h[15], dd.w, z1);
      float z = z0 + z1;
      z += __shfl_xor(z, 1);
      z += sB1[r];
      float sg = 1.f/(1.f+__expf(-z));
      dp1 = 0.909f*sg*(1.f + z*(1.f-sg));
      if ((t & 3) == 0) sH1[r] = (_Float16)(0.909f*z*sg);
    }
    __syncthreads();
    // ph2: z2 = W2@h1 + b2. (r,m): 64-col half, 32 dot2, 1 shfl.
    {
      const uint4* h4 = (const uint4*)sH1;
      float z0 = 0.f, z1 = 0.f;
      #pragma unroll
      for (int q=0; q<8; q++){
        uint4 v = h4[m*8 + q];
        z0 = dot2(w2h[4*q+0], v.x, z0); z1 = dot2(w2h[4*q+1], v.y, z1);
        z0 = dot2(w2h[4*q+2], v.z, z0); z1 = dot2(w2h[4*q+3], v.w, z1);
      }
      float z = z0 + z1;
      z += __shfl_xor(z, 1);
      z += sB2[r];
      float sg = 1.f/(1.f+__expf(-z));
      dp2 = 0.909f*sg*(1.f + z*(1.f-sg));
      if ((t & 3) == 0) sH2[r] = (_Float16)(0.909f*z*sg);
    }
    __syncthreads();
    // ph3: f = tanh(W3@h2 + b3). Owned row rowp, full 128 cols in regs.
    {
      const uint4* h4 = (const uint4*)sH2;    // broadcast reads
      float a0=0.f, a1=0.f, a2=0.f, a3=0.f;
      #pragma unroll
      for (int q=0; q<16; q++){
        uint4 hv = h4[q];
        a0 = dot2(w3r[4*q+0], hv.x, a0);
        a1 = dot2(w3r[4*q+1], hv.y, a1);
        a2 = dot2(w3r[4*q+2], hv.z, a2);
        a3 = dot2(w3r[4*q+3], hv.w, a3);
      }
      fr = tanh_fast((a0+a1)+(a2+a3) + sB3[rowp]);
      sFh[rowp] = (_Float16)fr;               // 8-way on 1 store: negligible
    }
    __syncthreads();
    // ph4: T1[r,i] = W1[r]·f_i (raw dirs), C-combine in-reg, D1 = dp1*(...).
    // (r,m,g): 4 raw i = 4g..4g+3, 32-col half each (64 dot2); m-shfl; then
    // two 4-j halves: 16 FMA + 4 shfl each; m==0 lanes write 2 dirs each.
    {
      const uint4* f4 = (const uint4*)sFh;
      float t1[4];
      #pragma unroll
      for (int k=0; k<4; k++){
        int i = 4*g + k;
        const uint4* fi = &f4[i*8 + m*4];
        uint4 a = fi[0], bb = fi[1], cc = fi[2], dd = fi[3];
        float z0 = dot2(w1h[0], a.x, 0.f), z1 = dot2(w1h[1], a.y, 0.f);
        z0 = dot2(w1h[2],  a.z, z0);  z1 = dot2(w1h[3],  a.w, z1);
        z0 = dot2(w1h[4],  bb.x, z0); z1 = dot2(w1h[5],  bb.y, z1);
        z0 = dot2(w1h[6],  bb.z, z0); z1 = dot2(w1h[7],  bb.w, z1);
        z0 = dot2(w1h[8],  cc.x, z0); z1 = dot2(w1h[9],  cc.y, z1);
        z0 = dot2(w1h[10], cc.z, z0); z1 = dot2(w1h[11], cc.w, z1);
        z0 = dot2(w1h[12], dd.x, z0); z1 = dot2(w1h[13], dd.y, z1);
        z0 = dot2(w1h[14], dd.z, z0); z1 = dot2(w1h[15], dd.w, z1);
        float z = z0 + z1;
        z += __shfl_xor(z, 1);                // m-halves
        t1[k] = z;
      }
      // j-half 1: j = 0..3
      {
        float pj[4];
        #pragma unroll
        for (int j=0; j<4; j++){
          float p = 0.f;
          #pragma unroll
          for (int k=0; k<4; k++) p += sC[j*8 + 4*g + k] * t1[k];
          pj[j] = p;
        }
        #pragma unroll
        for (int j=0; j<4; j++) pj[j] += __shfl_xor(pj[j], 2);  // g-halves
        if (m == 0){
          int j0 = 2*g;                       // g=0 -> j0,1 ; g=1 -> j2,3
          sD1[(j0  )*DSTR + r] = (_Float16)(dp1*pj[j0  ]);
          sD1[(j0+1)*DSTR + r] = (_Float16)(dp1*pj[j0+1]);
        }
      }
      // j-half 2: j = 4..7
      {
        float pj[4];
        #pragma unroll
        for (int j=0; j<4; j++){
          float p = 0.f;
          #pragma unroll
          for (int k=0; k<4; k++) p += sC[(j+4)*8 + 4*g + k] * t1[k];
          pj[j] = p;
        }
        #pragma unroll
        for (int j=0; j<4; j++) pj[j] += __shfl_xor(pj[j], 2);
        if (m == 0){
          int j0 = 2*g;
          sD1[(4+j0  )*DSTR + r] = (_Float16)(dp1*pj[j0  ]);
          sD1[(4+j0+1)*DSTR + r] = (_Float16)(dp1*pj[j0+1]);
        }
      }
    }
    __syncthreads();
    // ph5: D2[d] = dp2*(W2@D1[d]). (r,m,g): 4 dirs x 64-col half, 128 dot2.
    {
      const uint4* d4 = (const uint4*)sD1;
      #pragma unroll
      for (int k=0; k<4; k++){
        int dir = 4*g + k;
        const uint4* dd = &d4[dir*17 + m*8];
        float z0 = 0.f, z1 = 0.f;
        #pragma unroll
        for (int q=0; q<8; q++){
          uint4 v = dd[q];
          z0 = dot2(w2h[4*q+0], v.x, z0); z1 = dot2(w2h[4*q+1], v.y, z1);
          z0 = dot2(w2h[4*q+2], v.z, z0); z1 = dot2(w2h[4*q+3], v.w, z1);
        }
        float z = z0 + z1;
        z += __shfl_xor(z, 1);
        if (m == 0) sD2[dir*DSTR + r] = (_Float16)(dp2*z);
      }
    }
    __syncthreads();
    // ph6 (+ph7 fused): T3 = W3[rowp]·D2[jown]; contribution; 3-shfl k[a];
    // j0-lanes do Heun update. No sCon, no extra barrier.
    {
      const uint4* d4 = (const uint4*)&sD2[jown*DSTR];
      float a0=0.f, a1=0.f, a2=0.f, a3=0.f;
      #pragma unroll
      for (int q=0; q<16; q++){
        uint4 dv = d4[q];
        a0 = dot2(w3r[4*q+0], dv.x, a0);
        a1 = dot2(w3r[4*q+1], dv.y, a1);
        a2 = dot2(w3r[4*q+2], dv.z, a2);
        a3 = dot2(w3r[4*q+3], dv.w, a3);
      }
      float z = (a0+a1)+(a2+a3);
      float c = gcur[jown]*fr + (1.f - fr*fr)*z;
      c += __shfl_xor(c, 1);
      c += __shfl_xor(c, 2);
      c += __shfl_xor(c, 4);                  // k[aown] in all 8 lanes
      if (jown == 0){
        if (mode == 0){
          k1save = c;
          sYinp[aown] = (_Float16)(sY[aown] + c);
        } else {
          float yn = sY[aown] + 0.5f*(k1save + c);
          sY[aown] = yn;
          sYinp[aown] = (_Float16)yn;
        }
      }
    }
  };

  // ---- main scan over windows ----
  for (int s = 0; s < NWIN; s++){
    const float* gcur = &sG[s*LSIG];
    EVAL(gcur, 0, s);
    EVAL(gcur, 1, s);
  }
  __syncthreads();
  if (t < 4){
    float z = sBr[t] + sSh[0];
    #pragma unroll 8
    for (int a=0; a<64; a++) z += sWr[t*64+a]*sY[a];
    outp[(b*33 + 32)*4 + t] = z;
  }
}

extern "C" void kernel_launch(void* const* d_in, const int* in_sizes, int n_in,
                              void* d_out, int out_size, void* d_ws, size_t ws_size,
                              hipStream_t stream) {
  cde_kernel<<<dim3(NBATCH), dim3(512), 0, stream>>>(
      (const float*)d_in[0],
      (const float*)d_in[1],  (const float*)d_in[2],
      (const float*)d_in[3],  (const float*)d_in[4],
      (const float*)d_in[5],  (const float*)d_in[6],
      (const float*)d_in[7],  (const float*)d_in[8],
      (const float*)d_in[9],  (const float*)d_in[10],
      (const float*)d_in[11], (const float*)d_in[12],
      (const float*)d_in[13],
      (float*)d_out);
}

// Round 14
// 332.137 us; speedup vs baseline: 1.1652x; 1.0854x over previous
//
#include <hip/hip_runtime.h>

// log-ODE Neural CDE. B=32 chains, 32 windows, Heun = 2 evals/window.
// fp32 in/out, f32 accum, f16 weights/activations (v_dot2_f32_f16).
// 512 threads (8 waves, 2/SIMD), one block per batch element; W1/W2 halves +
// full W3 row per thread in registers (112 u32). amdgpu_waves_per_eu(2,2)
// requests the 256-VGPR budget (R10 got 128 and spilled ~15 regs).
// 4-acc dot2 chains; v_rcp_f32 for sigmoid/tanh critical path.
#define NBATCH 32
#define LPATH  513
#define NWIN   32
#define LSIG   36
#define DSTR   136   // [dir] stride sD1/sD2 (f16) = 17 uint4
#define USTR   72    // [dir] stride sU (f16) = 9 uint4

typedef unsigned int u32;
typedef _Float16 h2 __attribute__((ext_vector_type(2)));

__device__ __forceinline__ u32 pkh(float a, float b){
  return __builtin_bit_cast(u32, __builtin_amdgcn_cvt_pkrtz(a, b));
}
__device__ __forceinline__ float dot2(u32 a, u32 b, float c){
#if __has_builtin(__builtin_amdgcn_fdot2)
  return __builtin_amdgcn_fdot2(__builtin_bit_cast(h2,a),
                                __builtin_bit_cast(h2,b), c, false);
#else
  h2 x = __builtin_bit_cast(h2,a), y = __builtin_bit_cast(h2,b);
  return c + (float)x[0]*(float)y[0] + (float)x[1]*(float)y[1];
#endif
}
__device__ __forceinline__ float frcp(float x){
#if __has_builtin(__builtin_amdgcn_rcpf)
  return __builtin_amdgcn_rcpf(x);
#else
  return 1.f/x;
#endif
}
__device__ __forceinline__ float tanh_fast(float x){
  float e = __expf(2.f*x);
  return 1.f - 2.f*frcp(e+1.f);
}

extern "C" __global__
__attribute__((amdgpu_flat_work_group_size(512, 512), amdgpu_waves_per_eu(2, 2)))
void cde_kernel(const float* __restrict__ cv,
                const float* __restrict__ Wi1g, const float* __restrict__ bi1g,
                const float* __restrict__ Wi2g, const float* __restrict__ bi2g,
                const float* __restrict__ W1g,  const float* __restrict__ b1g,
                const float* __restrict__ W2g,  const float* __restrict__ b2g,
                const float* __restrict__ W3g,  const float* __restrict__ b3g,
                const float* __restrict__ Wrg,  const float* __restrict__ brg,
                const float* __restrict__ shg,
                float* __restrict__ outp)
{
  // ---- LDS (~17 KB) ----
  __shared__ float sG[NWIN*LSIG];
  __shared__ __align__(16) float sF[512];
  __shared__ float sCon[512];
  __shared__ float sB3[512];
  __shared__ float sB1[128], sB2[128];
  __shared__ __align__(16) float sWr[256];
  __shared__ float sBr[4], sSh[1];
  __shared__ float sC[64];
  __shared__ float sY[64], sK1[64], sLw[64];
  __shared__ __align__(16) _Float16 sYinp[64];
  __shared__ __align__(16) _Float16 sH1[128];
  __shared__ __align__(16) _Float16 sH2[128];
  __shared__ __align__(16) _Float16 sU [8*USTR];
  __shared__ __align__(16) _Float16 sD1[8*DSTR];
  __shared__ __align__(16) _Float16 sD2[8*DSTR];

  const int t  = threadIdx.x;        // 0..511
  const int b  = blockIdx.x;
  const int r  = t >> 2;             // 0..127 (ph1/2/4/5 row)
  const int m  = t & 1;              // col half
  const int g  = (t >> 1) & 1;       // dir group (4 dirs each)
  const int j6 = t >> 6;             // dir for ph3/6 row block (row = t)

  // ---- init biases / readout ----
  if (t < 512) sB3[t] = b3g[t];
  if (t < 128){ sB1[t] = b1g[t]; sB2[t] = b2g[t]; }
  if (t < 256) sWr[t] = Wrg[t];
  if (t < 4)   sBr[t] = brg[t];
  if (t == 0)  sSh[0] = shg[0];

  // ---- depth-2 Lyndon log-signatures, one window per thread (t<32) ----
  if (t < NWIN){
    const float4* cv4 = (const float4*)cv;
    const int base = (b*LPATH + t*16)*2;
    float cur[8], pre[8], acc[8], lv[28];
    { float4 a = cv4[base], d = cv4[base+1];
      cur[0]=a.x;cur[1]=a.y;cur[2]=a.z;cur[3]=a.w;
      cur[4]=d.x;cur[5]=d.y;cur[6]=d.z;cur[7]=d.w; }
    #pragma unroll
    for (int d=0; d<8; d++){ pre[d]=0.f; acc[d]=0.f; }
    #pragma unroll
    for (int p=0; p<28; p++) lv[p]=0.f;
    for (int w=1; w<=16; w++){
      float nxt[8], inc[8];
      { float4 a = cv4[base+2*w], d = cv4[base+2*w+1];
        nxt[0]=a.x;nxt[1]=a.y;nxt[2]=a.z;nxt[3]=a.w;
        nxt[4]=d.x;nxt[5]=d.y;nxt[6]=d.z;nxt[7]=d.w; }
      #pragma unroll
      for (int d=0; d<8; d++) inc[d] = nxt[d]-cur[d];
      int p=0;
      #pragma unroll
      for (int i=0; i<8; i++)
        #pragma unroll
        for (int j2=i+1; j2<8; j2++){ lv[p] += pre[i]*inc[j2] - pre[j2]*inc[i]; p++; }
      #pragma unroll
      for (int d=0; d<8; d++){ acc[d]+=inc[d]; pre[d]+=inc[d]; cur[d]=nxt[d]; }
    }
    float* gd = &sG[t*LSIG];
    #pragma unroll
    for (int d=0; d<8; d++) gd[d] = acc[d];
    #pragma unroll
    for (int p=0; p<28; p++) gd[8+p] = 0.5f*lv[p];
  }

  // ---- y0 = Wi2 @ lipswish(Wi1 @ x0 + bi1) + bi2 ----
  if (t < 64){
    float z = bi1g[t];
    #pragma unroll
    for (int d=0; d<8; d++) z += Wi1g[t*8+d] * cv[(b*LPATH)*8 + d];
    float s = frcp(1.f+__expf(-z));
    sLw[t] = 0.909f*z*s;
  }
  __syncthreads();
  if (t < 64){
    float z = bi2g[t];
    #pragma unroll 8
    for (int k=0; k<64; k++) z += Wi2g[t*64+k] * sLw[k];
    sY[t] = z;
    sYinp[t] = (_Float16)z;
  }
  __syncthreads();
  if (t < 4){
    float z = sBr[t] + sSh[0];
    #pragma unroll 8
    for (int a=0; a<64; a++) z += sWr[t*64+a]*sY[a];
    outp[(b*33 + 0)*4 + t] = z;
  }

  // ---- per-thread weight registers: 16 + 32 + 64 = 112 u32 (f16 pairs) ----
  u32 w1h[16], w2h[32], w3r[64];
  {
    const float2* W1f2 = (const float2*)W1g;
    #pragma unroll
    for (int i=0; i<16; i++){ float2 v = W1f2[r*32 + m*16 + i]; w1h[i] = pkh(v.x, v.y); }
    const float2* W2f2 = (const float2*)W2g;
    #pragma unroll
    for (int i=0; i<32; i++){ float2 v = W2f2[r*64 + m*32 + i]; w2h[i] = pkh(v.x, v.y); }
    const float4* W3f4 = (const float4*)W3g;
    #pragma unroll
    for (int k=0; k<32; k++){
      float4 v = W3f4[t*32 + k];
      w3r[2*k]   = pkh(v.x, v.y);
      w3r[2*k+1] = pkh(v.z, v.w);
    }
  }

  // One vector-field eval. mode 0: k1 (+fused sC, readout). mode 1: k2+Heun.
  auto EVAL = [&](const float* gcur, int mode, int s){
    __syncthreads();
    float dp1, dp2, fr;
    // ph1: z1 = W1@y + b1. (r,m): 32-col half, 16 dot2 (4 acc), 1 shfl.
    {
      if (mode == 0){
        if (t < 64){                          // bracket coeffs C[j*8+i]
          int j = t >> 3, i = t & 7;
          float v = 0.f;
          if (i < j)      v =  gcur[8 + (7*i - (i*(i-1))/2 + (j-i-1))];
          else if (i > j) v = -gcur[8 + (7*j - (j*(j-1))/2 + (i-j-1))];
          sC[t] = v;
        }
        if (s > 0 && t >= 504 && t < 508){    // readout of incoming y_s
          int o = t - 504;
          float z = sBr[o] + sSh[0];
          const float4* wr4 = (const float4*)&sWr[o*64];
          const float4* y4f = (const float4*)sY;
          #pragma unroll
          for (int q=0; q<16; q++){
            float4 w = wr4[q], y = y4f[q];
            z += w.x*y.x + w.y*y.y + w.z*y.z + w.w*y.w;
          }
          outp[(b*33 + s)*4 + o] = z;
        }
      }
      const uint4* y4 = (const uint4*)sYinp;
      uint4 a = y4[m*4+0], bb = y4[m*4+1], cc = y4[m*4+2], dd = y4[m*4+3];
      float z0 = dot2(w1h[0], a.x, 0.f),  z1 = dot2(w1h[1], a.y, 0.f);
      float z2 = dot2(w1h[2], a.z, 0.f),  z3 = dot2(w1h[3], a.w, 0.f);
      z0 = dot2(w1h[4],  bb.x, z0); z1 = dot2(w1h[5],  bb.y, z1);
      z2 = dot2(w1h[6],  bb.z, z2); z3 = dot2(w1h[7],  bb.w, z3);
      z0 = dot2(w1h[8],  cc.x, z0); z1 = dot2(w1h[9],  cc.y, z1);
      z2 = dot2(w1h[10], cc.z, z2); z3 = dot2(w1h[11], cc.w, z3);
      z0 = dot2(w1h[12], dd.x, z0); z1 = dot2(w1h[13], dd.y, z1);
      z2 = dot2(w1h[14], dd.z, z2); z3 = dot2(w1h[15], dd.w, z3);
      float z = (z0 + z1) + (z2 + z3);
      z += __shfl_xor(z, 1);
      z += sB1[r];
      float sg = frcp(1.f+__expf(-z));
      dp1 = 0.909f*sg*(1.f + z*(1.f-sg));
      if ((t & 3) == 0) sH1[r] = (_Float16)(0.909f*z*sg);
    }
    __syncthreads();
    // ph2: z2 = W2@h1 + b2. (r,m): 64-col half, 32 dot2 (4 acc), 1 shfl.
    {
      const uint4* h4 = (const uint4*)sH1;
      float z0 = 0.f, z1 = 0.f, z2 = 0.f, z3 = 0.f;
      #pragma unroll
      for (int q=0; q<8; q++){
        uint4 v = h4[m*8 + q];
        z0 = dot2(w2h[4*q+0], v.x, z0); z1 = dot2(w2h[4*q+1], v.y, z1);
        z2 = dot2(w2h[4*q+2], v.z, z2); z3 = dot2(w2h[4*q+3], v.w, z3);
      }
      float z = (z0 + z1) + (z2 + z3);
      z += __shfl_xor(z, 1);
      z += sB2[r];
      float sg = frcp(1.f+__expf(-z));
      dp2 = 0.909f*sg*(1.f + z*(1.f-sg));
      if ((t & 3) == 0) sH2[r] = (_Float16)(0.909f*z*sg);
    }
    __syncthreads();
    // ph3: f = tanh(W3@h2 + b3). Row t, full 128 cols in regs, 0 shfl.
    {
      const uint4* h4 = (const uint4*)sH2;    // wave-uniform broadcast reads
      float a0=0.f, a1=0.f, a2=0.f, a3=0.f;
      #pragma unroll
      for (int q=0; q<16; q++){
        uint4 hv = h4[q];
        a0 = dot2(w3r[4*q+0], hv.x, a0);
        a1 = dot2(w3r[4*q+1], hv.y, a1);
        a2 = dot2(w3r[4*q+2], hv.z, a2);
        a3 = dot2(w3r[4*q+3], hv.w, a3);
      }
      fr = tanh_fast((a0+a1)+(a2+a3) + sB3[t]);
      sF[t] = fr;
    }
    __syncthreads();
    // U-fold: u_j[bb] = sum_i C[j,i] f[i*64+bb]; 1:1, no dup.
    {
      int bb = t & 63;
      float u = 0.f;
      #pragma unroll
      for (int i=0; i<8; i++) u += sC[j6*8 + i] * sF[i*64 + bb];
      sU[j6*USTR + bb] = (_Float16)u;
    }
    __syncthreads();
    // ph4: D1[d] = dp1 * (W1 @ u_d). (r,m,g): 4 dirs x 32-col half.
    {
      const uint4* u4 = (const uint4*)sU;     // dir stride 9 uint4
      #pragma unroll
      for (int k=0; k<4; k++){
        int dir = 4*g + k;
        const uint4* ud = &u4[dir*9 + m*4];
        uint4 a = ud[0], bb = ud[1], cc = ud[2], dd = ud[3];
        float z0 = dot2(w1h[0], a.x, 0.f),  z1 = dot2(w1h[1], a.y, 0.f);
        float z2 = dot2(w1h[2], a.z, 0.f),  z3 = dot2(w1h[3], a.w, 0.f);
        z0 = dot2(w1h[4],  bb.x, z0); z1 = dot2(w1h[5],  bb.y, z1);
        z2 = dot2(w1h[6],  bb.z, z2); z3 = dot2(w1h[7],  bb.w, z3);
        z0 = dot2(w1h[8],  cc.x, z0); z1 = dot2(w1h[9],  cc.y, z1);
        z2 = dot2(w1h[10], cc.z, z2); z3 = dot2(w1h[11], cc.w, z3);
        z0 = dot2(w1h[12], dd.x, z0); z1 = dot2(w1h[13], dd.y, z1);
        z2 = dot2(w1h[14], dd.z, z2); z3 = dot2(w1h[15], dd.w, z3);
        float z = (z0 + z1) + (z2 + z3);
        z += __shfl_xor(z, 1);
        if (m == 0) sD1[dir*DSTR + r] = (_Float16)(dp1*z);
      }
    }
    __syncthreads();
    // ph5: D2[d] = dp2 * (W2 @ D1[d]). (r,m,g): 4 dirs x 64-col half, 4 acc.
    {
      const uint4* d4 = (const uint4*)sD1;    // dir stride 17 uint4
      #pragma unroll
      for (int k=0; k<4; k++){
        int dir = 4*g + k;
        const uint4* dd = &d4[dir*17 + m*8];
        float z0 = 0.f, z1 = 0.f, z2 = 0.f, z3 = 0.f;
        #pragma unroll
        for (int q=0; q<8; q++){
          uint4 v = dd[q];
          z0 = dot2(w2h[4*q+0], v.x, z0); z1 = dot2(w2h[4*q+1], v.y, z1);
          z2 = dot2(w2h[4*q+2], v.z, z2); z3 = dot2(w2h[4*q+3], v.w, z3);
        }
        float z = (z0 + z1) + (z2 + z3);
        z += __shfl_xor(z, 1);
        if (m == 0) sD2[dir*DSTR + r] = (_Float16)(dp2*z);
      }
    }
    __syncthreads();
    // ph6: T3[t] = W3[t]·D2[j6]; contribution. Row t, regs, 0 shfl.
    {
      const uint4* d4 = (const uint4*)&sD2[j6*DSTR];  // wave-uniform
      float a0=0.f, a1=0.f, a2=0.f, a3=0.f;
      #pragma unroll
      for (int q=0; q<16; q++){
        uint4 dv = d4[q];
        a0 = dot2(w3r[4*q+0], dv.x, a0);
        a1 = dot2(w3r[4*q+1], dv.y, a1);
        a2 = dot2(w3r[4*q+2], dv.z, a2);
        a3 = dot2(w3r[4*q+3], dv.w, a3);
      }
      float z = (a0+a1)+(a2+a3);
      sCon[t] = gcur[j6]*fr + (1.f - fr*fr)*z;
    }
    __syncthreads();
    // ph7: k[a] = sum_j contrib; fused Heun updates.
    if (t < 64){
      float k = 0.f;
      #pragma unroll
      for (int j=0; j<8; j++) k += sCon[j*64 + t];
      if (mode == 0){
        sK1[t] = k;
        sYinp[t] = (_Float16)(sY[t] + k);     // midpoint input for eval2
      } else {
        float yn = sY[t] + 0.5f*(sK1[t] + k);
        sY[t] = yn;
        sYinp[t] = (_Float16)yn;
      }
    }
  };

  // ---- main scan over windows ----
  for (int s = 0; s < NWIN; s++){
    const float* gcur = &sG[s*LSIG];
    EVAL(gcur, 0, s);
    EVAL(gcur, 1, s);
  }
  __syncthreads();
  if (t < 4){                                 // final readout (y after win 31)
    float z = sBr[t] + sSh[0];
    #pragma unroll 8
    for (int a=0; a<64; a++) z += sWr[t*64+a]*sY[a];
    outp[(b*33 + 32)*4 + t] = z;
  }
}

extern "C" void kernel_launch(void* const* d_in, const int* in_sizes, int n_in,
                              void* d_out, int out_size, void* d_ws, size_t ws_size,
                              hipStream_t stream) {
  cde_kernel<<<dim3(NBATCH), dim3(512), 0, stream>>>(
      (const float*)d_in[0],
      (const float*)d_in[1],  (const float*)d_in[2],
      (const float*)d_in[3],  (const float*)d_in[4],
      (const float*)d_in[5],  (const float*)d_in[6],
      (const float*)d_in[7],  (const float*)d_in[8],
      (const float*)d_in[9],  (const float*)d_in[10],
      (const float*)d_in[11], (const float*)d_in[12],
      (const float*)d_in[13],
      (float*)d_out);
}

// Round 15
// 331.199 us; speedup vs baseline: 1.1685x; 1.0028x over previous
//
#include <hip/hip_runtime.h>

// log-ODE Neural CDE. B=32 chains, 32 windows, Heun = 2 evals/window.
// fp32 in/out, f32 accum, f16 weights/activations (v_dot2_f32_f16).
// 512 threads (8 waves, 2/SIMD), one block per batch element; W1/W2 halves +
// full W3 row per thread in registers (112 u32).
// R15: octet permutation rowp = (t&7)*64 + (t>>3) -> the 8 lanes of an octet
// hold f_i[a] for one hidden unit a. U-fold becomes an 8-shfl in-register
// combine inside ph3 (Ufold phase + sF deleted); k[a] becomes a 3-shfl octet
// reduction inside ph6 (ph7 + sCon deleted). 6 barriers/eval (was 8).
#define NBATCH 32
#define LPATH  513
#define NWIN   32
#define LSIG   36
#define DSTR   136   // [dir] stride sD1/sD2 (f16) = 17 uint4
#define USTR   72    // [dir] stride sU (f16) = 9 uint4

typedef unsigned int u32;
typedef _Float16 h2 __attribute__((ext_vector_type(2)));

__device__ __forceinline__ u32 pkh(float a, float b){
  return __builtin_bit_cast(u32, __builtin_amdgcn_cvt_pkrtz(a, b));
}
__device__ __forceinline__ float dot2(u32 a, u32 b, float c){
#if __has_builtin(__builtin_amdgcn_fdot2)
  return __builtin_amdgcn_fdot2(__builtin_bit_cast(h2,a),
                                __builtin_bit_cast(h2,b), c, false);
#else
  h2 x = __builtin_bit_cast(h2,a), y = __builtin_bit_cast(h2,b);
  return c + (float)x[0]*(float)y[0] + (float)x[1]*(float)y[1];
#endif
}
__device__ __forceinline__ float frcp(float x){
#if __has_builtin(__builtin_amdgcn_rcpf)
  return __builtin_amdgcn_rcpf(x);
#else
  return 1.f/x;
#endif
}
__device__ __forceinline__ float tanh_fast(float x){
  float e = __expf(2.f*x);
  return 1.f - 2.f*frcp(e+1.f);
}

extern "C" __global__
__attribute__((amdgpu_flat_work_group_size(512, 512), amdgpu_waves_per_eu(2, 2)))
void cde_kernel(const float* __restrict__ cv,
                const float* __restrict__ Wi1g, const float* __restrict__ bi1g,
                const float* __restrict__ Wi2g, const float* __restrict__ bi2g,
                const float* __restrict__ W1g,  const float* __restrict__ b1g,
                const float* __restrict__ W2g,  const float* __restrict__ b2g,
                const float* __restrict__ W3g,  const float* __restrict__ b3g,
                const float* __restrict__ Wrg,  const float* __restrict__ brg,
                const float* __restrict__ shg,
                float* __restrict__ outp)
{
  // ---- LDS (~12 KB) ----
  __shared__ float sG[NWIN*LSIG];
  __shared__ float sB3p[512];               // b3 permuted: sB3p[t] = b3[rowp]
  __shared__ float sB1[128], sB2[128];
  __shared__ __align__(16) float sWr[256];
  __shared__ float sBr[4], sSh[1];
  __shared__ float sC[64];
  __shared__ float sY[64], sLw[64];
  __shared__ __align__(16) _Float16 sYinp[64];
  __shared__ __align__(16) _Float16 sH1[128];
  __shared__ __align__(16) _Float16 sH2[128];
  __shared__ __align__(16) _Float16 sU [8*USTR];
  __shared__ __align__(16) _Float16 sD1[8*DSTR];
  __shared__ __align__(16) _Float16 sD2[8*DSTR];

  const int t    = threadIdx.x;      // 0..511
  const int b    = blockIdx.x;
  const int r    = t >> 2;           // 0..127 (ph1/2/4/5 row)
  const int m    = t & 1;            // col half
  const int g    = (t >> 1) & 1;     // dir group (4 dirs each)
  const int jown = t & 7;            // owned dir    (ph3/6)
  const int aown = t >> 3;           // owned hidden (ph3/6)
  const int rowp = jown*64 + aown;   // owned W3 row (permuted)

  // ---- init biases / readout ----
  sB3p[t] = b3g[rowp];
  if (t < 128){ sB1[t] = b1g[t]; sB2[t] = b2g[t]; }
  if (t < 256) sWr[t] = Wrg[t];
  if (t < 4)   sBr[t] = brg[t];
  if (t == 0)  sSh[0] = shg[0];

  // ---- depth-2 Lyndon log-signatures, one window per thread (t<32) ----
  if (t < NWIN){
    const float4* cv4 = (const float4*)cv;
    const int base = (b*LPATH + t*16)*2;
    float cur[8], pre[8], acc[8], lv[28];
    { float4 a = cv4[base], d = cv4[base+1];
      cur[0]=a.x;cur[1]=a.y;cur[2]=a.z;cur[3]=a.w;
      cur[4]=d.x;cur[5]=d.y;cur[6]=d.z;cur[7]=d.w; }
    #pragma unroll
    for (int d=0; d<8; d++){ pre[d]=0.f; acc[d]=0.f; }
    #pragma unroll
    for (int p=0; p<28; p++) lv[p]=0.f;
    for (int w=1; w<=16; w++){
      float nxt[8], inc[8];
      { float4 a = cv4[base+2*w], d = cv4[base+2*w+1];
        nxt[0]=a.x;nxt[1]=a.y;nxt[2]=a.z;nxt[3]=a.w;
        nxt[4]=d.x;nxt[5]=d.y;nxt[6]=d.z;nxt[7]=d.w; }
      #pragma unroll
      for (int d=0; d<8; d++) inc[d] = nxt[d]-cur[d];
      int p=0;
      #pragma unroll
      for (int i=0; i<8; i++)
        #pragma unroll
        for (int j2=i+1; j2<8; j2++){ lv[p] += pre[i]*inc[j2] - pre[j2]*inc[i]; p++; }
      #pragma unroll
      for (int d=0; d<8; d++){ acc[d]+=inc[d]; pre[d]+=inc[d]; cur[d]=nxt[d]; }
    }
    float* gd = &sG[t*LSIG];
    #pragma unroll
    for (int d=0; d<8; d++) gd[d] = acc[d];
    #pragma unroll
    for (int p=0; p<28; p++) gd[8+p] = 0.5f*lv[p];
  }

  // ---- y0 = Wi2 @ lipswish(Wi1 @ x0 + bi1) + bi2 ----
  if (t < 64){
    float z = bi1g[t];
    #pragma unroll
    for (int d=0; d<8; d++) z += Wi1g[t*8+d] * cv[(b*LPATH)*8 + d];
    float s = frcp(1.f+__expf(-z));
    sLw[t] = 0.909f*z*s;
  }
  __syncthreads();
  if (t < 64){
    float z = bi2g[t];
    #pragma unroll 8
    for (int k=0; k<64; k++) z += Wi2g[t*64+k] * sLw[k];
    sY[t] = z;
    sYinp[t] = (_Float16)z;
  }
  __syncthreads();
  if (t < 4){
    float z = sBr[t] + sSh[0];
    #pragma unroll 8
    for (int a=0; a<64; a++) z += sWr[t*64+a]*sY[a];
    outp[(b*33 + 0)*4 + t] = z;
  }

  // ---- per-thread weight registers: 16 + 32 + 64 = 112 u32 (f16 pairs) ----
  u32 w1h[16], w2h[32], w3r[64];
  {
    const float2* W1f2 = (const float2*)W1g;
    #pragma unroll
    for (int i=0; i<16; i++){ float2 v = W1f2[r*32 + m*16 + i]; w1h[i] = pkh(v.x, v.y); }
    const float2* W2f2 = (const float2*)W2g;
    #pragma unroll
    for (int i=0; i<32; i++){ float2 v = W2f2[r*64 + m*32 + i]; w2h[i] = pkh(v.x, v.y); }
    const float4* W3f4 = (const float4*)W3g;
    #pragma unroll
    for (int k=0; k<32; k++){
      float4 v = W3f4[rowp*32 + k];
      w3r[2*k]   = pkh(v.x, v.y);
      w3r[2*k+1] = pkh(v.z, v.w);
    }
  }

  float k1save = 0.f;   // k1 for Heun, lives in jown==0 lanes

  // One vector-field eval. mode 0: k1 (+fused sC, readout). mode 1: k2+Heun.
  auto EVAL = [&](const float* gcur, int mode, int s){
    __syncthreads();                          // sYinp, sY, sC coherent
    float dp1, dp2, fr;
    // ph1: z1 = W1@y + b1. (r,m): 32-col half, 16 dot2 (4 acc), 1 shfl.
    {
      if (mode == 0){
        if (t < 64){                          // bracket coeffs C[j*8+i]
          int j = t >> 3, i = t & 7;
          float v = 0.f;
          if (i < j)      v =  gcur[8 + (7*i - (i*(i-1))/2 + (j-i-1))];
          else if (i > j) v = -gcur[8 + (7*j - (j*(j-1))/2 + (i-j-1))];
          sC[t] = v;
        }
        if (s > 0 && t >= 504 && t < 508){    // readout of incoming y_s
          int o = t - 504;
          float z = sBr[o] + sSh[0];
          const float4* wr4 = (const float4*)&sWr[o*64];
          const float4* y4f = (const float4*)sY;
          #pragma unroll
          for (int q=0; q<16; q++){
            float4 w = wr4[q], y = y4f[q];
            z += w.x*y.x + w.y*y.y + w.z*y.z + w.w*y.w;
          }
          outp[(b*33 + s)*4 + o] = z;
        }
      }
      const uint4* y4 = (const uint4*)sYinp;
      uint4 a = y4[m*4+0], bb = y4[m*4+1], cc = y4[m*4+2], dd = y4[m*4+3];
      float z0 = dot2(w1h[0], a.x, 0.f),  z1 = dot2(w1h[1], a.y, 0.f);
      float z2 = dot2(w1h[2], a.z, 0.f),  z3 = dot2(w1h[3], a.w, 0.f);
      z0 = dot2(w1h[4],  bb.x, z0); z1 = dot2(w1h[5],  bb.y, z1);
      z2 = dot2(w1h[6],  bb.z, z2); z3 = dot2(w1h[7],  bb.w, z3);
      z0 = dot2(w1h[8],  cc.x, z0); z1 = dot2(w1h[9],  cc.y, z1);
      z2 = dot2(w1h[10], cc.z, z2); z3 = dot2(w1h[11], cc.w, z3);
      z0 = dot2(w1h[12], dd.x, z0); z1 = dot2(w1h[13], dd.y, z1);
      z2 = dot2(w1h[14], dd.z, z2); z3 = dot2(w1h[15], dd.w, z3);
      float z = (z0 + z1) + (z2 + z3);
      z += __shfl_xor(z, 1);
      z += sB1[r];
      float sg = frcp(1.f+__expf(-z));
      dp1 = 0.909f*sg*(1.f + z*(1.f-sg));
      if ((t & 3) == 0) sH1[r] = (_Float16)(0.909f*z*sg);
    }
    __syncthreads();
    // ph2: z2 = W2@h1 + b2. (r,m): 64-col half, 32 dot2 (4 acc), 1 shfl.
    {
      const uint4* h4 = (const uint4*)sH1;
      float z0 = 0.f, z1 = 0.f, z2 = 0.f, z3 = 0.f;
      #pragma unroll
      for (int q=0; q<8; q++){
        uint4 v = h4[m*8 + q];
        z0 = dot2(w2h[4*q+0], v.x, z0); z1 = dot2(w2h[4*q+1], v.y, z1);
        z2 = dot2(w2h[4*q+2], v.z, z2); z3 = dot2(w2h[4*q+3], v.w, z3);
      }
      float z = (z0 + z1) + (z2 + z3);
      z += __shfl_xor(z, 1);
      z += sB2[r];
      float sg = frcp(1.f+__expf(-z));
      dp2 = 0.909f*sg*(1.f + z*(1.f-sg));
      if ((t & 3) == 0) sH2[r] = (_Float16)(0.909f*z*sg);
    }
    __syncthreads();
    // ph3 (+U-fold fused): fr = tanh(W3[rowp]@h2 + b3[rowp]); then the
    // octet (lanes a*8..a*8+7 hold f_i[a], i=0..7) combines u_j[a] via
    // 8 in-register shfl broadcasts. Writes sU only — sF eliminated.
    {
      const uint4* h4 = (const uint4*)sH2;    // wave-uniform broadcast reads
      float a0=0.f, a1=0.f, a2=0.f, a3=0.f;
      #pragma unroll
      for (int q=0; q<16; q++){
        uint4 hv = h4[q];
        a0 = dot2(w3r[4*q+0], hv.x, a0);
        a1 = dot2(w3r[4*q+1], hv.y, a1);
        a2 = dot2(w3r[4*q+2], hv.z, a2);
        a3 = dot2(w3r[4*q+3], hv.w, a3);
      }
      fr = tanh_fast((a0+a1)+(a2+a3) + sB3p[t]);
      // u_{jown}[aown] = sum_i C[jown,i] * f_i[aown]
      const int base = t & ~7;                // octet base lane
      float u = 0.f;
      #pragma unroll
      for (int i=0; i<8; i++){
        float fi = __shfl(fr, base + i);      // f_i[aown] from octet lane i
        u += sC[jown*8 + i] * fi;
      }
      sU[jown*USTR + aown] = (_Float16)u;
    }
    __syncthreads();
    // ph4: D1[d] = dp1 * (W1 @ u_d). (r,m,g): 4 dirs x 32-col half.
    {
      const uint4* u4 = (const uint4*)sU;     // dir stride 9 uint4
      #pragma unroll
      for (int k=0; k<4; k++){
        int dir = 4*g + k;
        const uint4* ud = &u4[dir*9 + m*4];
        uint4 a = ud[0], bb = ud[1], cc = ud[2], dd = ud[3];
        float z0 = dot2(w1h[0], a.x, 0.f),  z1 = dot2(w1h[1], a.y, 0.f);
        float z2 = dot2(w1h[2], a.z, 0.f),  z3 = dot2(w1h[3], a.w, 0.f);
        z0 = dot2(w1h[4],  bb.x, z0); z1 = dot2(w1h[5],  bb.y, z1);
        z2 = dot2(w1h[6],  bb.z, z2); z3 = dot2(w1h[7],  bb.w, z3);
        z0 = dot2(w1h[8],  cc.x, z0); z1 = dot2(w1h[9],  cc.y, z1);
        z2 = dot2(w1h[10], cc.z, z2); z3 = dot2(w1h[11], cc.w, z3);
        z0 = dot2(w1h[12], dd.x, z0); z1 = dot2(w1h[13], dd.y, z1);
        z2 = dot2(w1h[14], dd.z, z2); z3 = dot2(w1h[15], dd.w, z3);
        float z = (z0 + z1) + (z2 + z3);
        z += __shfl_xor(z, 1);
        if (m == 0) sD1[dir*DSTR + r] = (_Float16)(dp1*z);
      }
    }
    __syncthreads();
    // ph5: D2[d] = dp2 * (W2 @ D1[d]). (r,m,g): 4 dirs x 64-col half, 4 acc.
    {
      const uint4* d4 = (const uint4*)sD1;    // dir stride 17 uint4
      #pragma unroll
      for (int k=0; k<4; k++){
        int dir = 4*g + k;
        const uint4* dd = &d4[dir*17 + m*8];
        float z0 = 0.f, z1 = 0.f, z2 = 0.f, z3 = 0.f;
        #pragma unroll
        for (int q=0; q<8; q++){
          uint4 v = dd[q];
          z0 = dot2(w2h[4*q+0], v.x, z0); z1 = dot2(w2h[4*q+1], v.y, z1);
          z2 = dot2(w2h[4*q+2], v.z, z2); z3 = dot2(w2h[4*q+3], v.w, z3);
        }
        float z = (z0 + z1) + (z2 + z3);
        z += __shfl_xor(z, 1);
        if (m == 0) sD2[dir*DSTR + r] = (_Float16)(dp2*z);
      }
    }
    __syncthreads();
    // ph6 (+ph7 fused): T3 = W3[rowp]·D2[jown]; contribution; octet 3-shfl
    // reduce -> k[aown]; jown==0 lanes apply Heun. sCon eliminated.
    {
      const uint4* d4 = (const uint4*)&sD2[jown*DSTR];  // per-lane dir, banks disjoint
      float a0=0.f, a1=0.f, a2=0.f, a3=0.f;
      #pragma unroll
      for (int q=0; q<16; q++){
        uint4 dv = d4[q];
        a0 = dot2(w3r[4*q+0], dv.x, a0);
        a1 = dot2(w3r[4*q+1], dv.y, a1);
        a2 = dot2(w3r[4*q+2], dv.z, a2);
        a3 = dot2(w3r[4*q+3], dv.w, a3);
      }
      float z = (a0+a1)+(a2+a3);
      float c = gcur[jown]*fr + (1.f - fr*fr)*z;
      c += __shfl_xor(c, 1);
      c += __shfl_xor(c, 2);
      c += __shfl_xor(c, 4);                  // k[aown] in all octet lanes
      if (jown == 0){
        if (mode == 0){
          k1save = c;
          sYinp[aown] = (_Float16)(sY[aown] + c);
        } else {
          float yn = sY[aown] + 0.5f*(k1save + c);
          sY[aown] = yn;
          sYinp[aown] = (_Float16)yn;
        }
      }
    }
  };

  // ---- main scan over windows ----
  for (int s = 0; s < NWIN; s++){
    const float* gcur = &sG[s*LSIG];
    EVAL(gcur, 0, s);
    EVAL(gcur, 1, s);
  }
  __syncthreads();
  if (t < 4){                                 // final readout (y after win 31)
    float z = sBr[t] + sSh[0];
    #pragma unroll 8
    for (int a=0; a<64; a++) z += sWr[t*64+a]*sY[a];
    outp[(b*33 + 32)*4 + t] = z;
  }
}

extern "C" void kernel_launch(void* const* d_in, const int* in_sizes, int n_in,
                              void* d_out, int out_size, void* d_ws, size_t ws_size,
                              hipStream_t stream) {
  cde_kernel<<<dim3(NBATCH), dim3(512), 0, stream>>>(
      (const float*)d_in[0],
      (const float*)d_in[1],  (const float*)d_in[2],
      (const float*)d_in[3],  (const float*)d_in[4],
      (const float*)d_in[5],  (const float*)d_in[6],
      (const float*)d_in[7],  (const float*)d_in[8],
      (const float*)d_in[9],  (const float*)d_in[10],
      (const float*)d_in[11], (const float*)d_in[12],
      (const float*)d_in[13],
      (float*)d_out);
}